// Round 7
// baseline (14893.239 us; speedup 1.0000x reference)
//
#include <hip/hip_runtime.h>
#include <cstdint>

#define NTAP 27
#define CH 32
static constexpr int N_LOW = 16384;
static constexpr int M_ALL = 131072;
static constexpr int NCHMAX = 2048;   // hard bound: M_ALL/64 chunks

// ---------------- init / gt_mask normalization ----------------

__global__ void k_init(int* cnt) {
    int t = threadIdx.x;
    if (t < 64) cnt[t] = 0;
    if (t == 0) cnt[8] = N_LOW;     // low-map row count
}

__global__ __launch_bounds__(256) void k_gt_detect(const unsigned char* __restrict__ p, int* flags) {
    int i = blockIdx.x * 256 + threadIdx.x;
    bool a = false, b = false;
    if (i < M_ALL) {
        unsigned char v = p[i];
        a = ((i & 3) != 0) && (v != 0);
        b = (v > 1);
    }
    unsigned long long ba = __ballot(a);
    unsigned long long bb = __ballot(b);
    if ((threadIdx.x & 63) == 0) {
        if (ba) atomicOr(&flags[32], 1);
        if (bb) atomicOr(&flags[33], 1);
    }
}

__global__ __launch_bounds__(256) void k_gt_norm(const unsigned char* __restrict__ p,
                                                 unsigned char* __restrict__ gt8,
                                                 const int* __restrict__ flags) {
    int i = blockIdx.x * 256 + threadIdx.x;
    if (i >= M_ALL) return;
    bool u8 = (flags[32] != 0) && (flags[33] == 0);
    unsigned char v;
    if (u8) v = (p[i] != 0) ? 1 : 0;
    else    v = (((const int*)p)[i] != 0) ? 1 : 0;
    gt8[i] = v;
}

__global__ __launch_bounds__(256) void k_iota(int* list) {
    int i = blockIdx.x * 256 + threadIdx.x;
    if (i < N_LOW) list[i] = i;
}

// ---------------- low-grid first conv (Cin=1) ----------------

__global__ __launch_bounds__(256) void k_conv_low0(const float* __restrict__ x,
                                                   const int* __restrict__ nbr,
                                                   const float* __restrict__ w0,
                                                   const float* __restrict__ b0,
                                                   float* __restrict__ out) {
    int g = blockIdx.x * 256 + threadIdx.x;
    int n = g >> 5, co = g & 31;
    float acc = b0[co];
    const int* nr = nbr + n * NTAP;
    for (int k = 0; k < NTAP; ++k) {
        int j = nr[k];
        if (j >= 0) acc += x[j] * w0[k * CH + co];
    }
    out[g] = fmaxf(acc, 0.f);
}

// ---------------- ordered compaction (count / scan / emit) ----------------

template<int FIRST>
__global__ __launch_bounds__(256) void k_vcount(unsigned char* __restrict__ valid,
                                                const unsigned char* __restrict__ gt8,
                                                const float* __restrict__ HS,
                                                const float* __restrict__ feats,
                                                float* __restrict__ F,
                                                int* __restrict__ bcnt, int so) {
    int m = blockIdx.x * 256 + threadIdx.x;
    int v;
    if (FIRST) {
        v = ((m & 7) == 0);
    } else {
        int ov = valid[m] & gt8[m];
        int sl = ((m & 7) == so);
        v = ov | sl;
        if (v) {
            const float4* src = (const float4*)((ov ? HS : feats) + (long)m * CH);
            float4* dst = (float4*)(F + (long)m * CH);
            #pragma unroll
            for (int i = 0; i < 8; ++i) dst[i] = src[i];
        }
    }
    valid[m] = (unsigned char)v;
    __shared__ int red[4];
    unsigned long long b = __ballot(v != 0);
    if ((threadIdx.x & 63) == 0) red[threadIdx.x >> 6] = __popcll(b);
    __syncthreads();
    if (threadIdx.x == 0) bcnt[blockIdx.x] = red[0] + red[1] + red[2] + red[3];
}

__global__ void k_scan512(const int* __restrict__ bcnt, int* __restrict__ boff,
                          int* __restrict__ cnt_out) {
    __shared__ int s[512];
    int t = threadIdx.x;
    int mine = bcnt[t];
    s[t] = mine;
    __syncthreads();
    for (int d = 1; d < 512; d <<= 1) {
        int v = (t >= d) ? s[t - d] : 0;
        __syncthreads();
        s[t] += v;
        __syncthreads();
    }
    boff[t] = s[t] - mine;
    if (t == 511) cnt_out[0] = s[511];
}

__global__ __launch_bounds__(256) void k_emit(const unsigned char* __restrict__ valid,
                                              const int* __restrict__ boff,
                                              int* __restrict__ list) {
    int m = blockIdx.x * 256 + threadIdx.x;
    int v = valid[m];
    __shared__ int wof[4];
    unsigned long long b = __ballot(v != 0);
    int lane = threadIdx.x & 63, w = threadIdx.x >> 6;
    int rank = __popcll(b & ((1ull << lane) - 1ull));
    if (lane == 0) wof[w] = __popcll(b);
    __syncthreads();
    int pre = 0;
    for (int i = 0; i < w; ++i) pre += wof[i];
    if (v) list[boff[blockIdx.x] + pre + rank] = m;
}

// ---------------- pair-list build per (chunk, tap): ballot-based, no atomics --------
// pent[(c*27+k)*64 + rank] = (lrow<<24) | j ; pcnt[c*27+k] = popcount.

template<int VAL>
__global__ __launch_bounds__(256) void k_pairs2(const int* __restrict__ nbr,
                                                const int* __restrict__ list,
                                                const int* __restrict__ d_count,
                                                const unsigned char* __restrict__ valid,
                                                int* __restrict__ pcnt,
                                                unsigned int* __restrict__ pent) {
    const int count = d_count[0];
    const int nch = (count + 63) >> 6;
    const int c = blockIdx.x;
    if (c >= nch) return;
    const int t = threadIdx.x, wave = t >> 6, lane = t & 63;
    const int gi = (c << 6) + lane;
    const int m = (gi < count) ? list[gi] : -1;
    const int* nr = nbr + (long)m * NTAP;
    for (int k = wave; k < NTAP; k += 4) {
        int j = -1;
        if (m >= 0) {
            j = nr[k];
            if (VAL && j >= 0 && !valid[j]) j = -1;
        }
        unsigned long long mask = __ballot(j >= 0);
        int rank = __popcll(mask & ((1ull << lane) - 1ull));
        if (j >= 0)
            pent[(((long)(c * NTAP + k)) << 6) | rank] = ((unsigned)lane << 24) | (unsigned)j;
        if (lane == 0) pcnt[c * NTAP + k] = __popcll(mask);
    }
}

// ---- pair-compacted conv: 4 waves split taps; SINGLE shared acc plane via LDS
// ---- float atomics (ds_add_f32). Stride 44 floats: 16B-aligned, ~2-way banks.

#define INV 0xFFFFFFFFu

template<int RELU, int ADD>
__global__ __launch_bounds__(256, 4) void k_convs(
    const float* __restrict__ f,
    float* __restrict__ out,
    const float* __restrict__ addsrc,
    const float* __restrict__ W,        // [27][32][32]
    const float* __restrict__ bias,     // [32]
    const int* __restrict__ list,
    const int* __restrict__ d_count,
    const int* __restrict__ pcnt,
    const unsigned int* __restrict__ pent)
{
    __shared__ float acc[64 * 44];       // 11264 B: shared atomic acc plane
    __shared__ float wb[4 * 1024];       // 16384 B: per-wave W[k]
    __shared__ float fb[4 * 16 * 36];    // 9216 B: per-wave staged rows
    const int count = d_count[0];
    const int nch = (count + 63) >> 6;
    const int c = blockIdx.x;
    if (c >= nch) return;
    const int t = threadIdx.x;
    const int wave = t >> 6, lane = t & 63;
    const int slot = lane >> 3, coq = lane & 7;
    const float4 z4f = make_float4(0.f, 0.f, 0.f, 0.f);
    for (int i = t; i < 704; i += 256) ((float4*)acc)[i] = z4f;   // 64*44/4
    __syncthreads();
    float* wbw = wb + wave * 1024;
    float* fbw = fb + wave * (16 * 36);
    const int base_ck = c * NTAP;

    for (int k = wave; k < NTAP; k += 4) {
        const int L = pcnt[base_ck + k];
        if (L == 0) continue;
        // stage W[k] (wave-local, contiguous)
        const float4* Wg = (const float4*)(W + (long)k * 1024);
        #pragma unroll
        for (int r = 0; r < 4; ++r) {
            float4 v = Wg[lane + 64 * r];
            *((float4*)(wbw + (lane + 64 * r) * 4)) = v;
        }
        const unsigned int* pk = pent + (((long)(base_ck + k)) << 6);
        // preload this slot's entries (batch b uses ent[2b], ent[2b+1])
        unsigned ent[8];
        #pragma unroll
        for (int r = 0; r < 8; ++r) {
            int idx = r * 8 + slot;
            ent[r] = (idx < L) ? pk[idx] : INV;
        }
        const int nb = (L + 15) >> 4;
        // prefetch batch 0
        unsigned u0 = ent[0], u1 = ent[1];
        float4 g0 = z4f, g1 = z4f;
        if (u0 != INV) g0 = ((const float4*)(f + (long)(u0 & 0xFFFFFFu) * CH))[coq];
        if (u1 != INV) g1 = ((const float4*)(f + (long)(u1 & 0xFFFFFFu) * CH))[coq];
        #pragma unroll
        for (int b = 0; b < 4; ++b) {
            if (b >= nb) break;
            // stage current batch (compiler inserts vmcnt wait on g0/g1)
            *((float4*)(fbw + slot * 72 + coq * 4)) = g0;
            *((float4*)(fbw + slot * 72 + 36 + coq * 4)) = g1;
            // issue next batch's gathers (overlap with FMA below)
            unsigned nu0 = INV, nu1 = INV;
            float4 n0 = z4f, n1 = z4f;
            if (b + 1 < 4 && b + 1 < nb) {
                nu0 = ent[2 * b + 2];
                nu1 = ent[2 * b + 3];
                if (nu0 != INV) n0 = ((const float4*)(f + (long)(nu0 & 0xFFFFFFu) * CH))[coq];
                if (nu1 != INV) n1 = ((const float4*)(f + (long)(nu1 & 0xFFFFFFu) * CH))[coq];
            }
            asm volatile("s_waitcnt lgkmcnt(0)" ::: "memory");
            __builtin_amdgcn_sched_barrier(0);
            float r00 = 0.f, r01 = 0.f, r02 = 0.f, r03 = 0.f;
            float r10 = 0.f, r11 = 0.f, r12 = 0.f, r13 = 0.f;
            #pragma unroll
            for (int c4 = 0; c4 < 8; ++c4) {
                float4 q0 = *((const float4*)(fbw + slot * 72 + c4 * 4));
                float4 q1 = *((const float4*)(fbw + slot * 72 + 36 + c4 * 4));
                const float* wp = wbw + c4 * 128 + coq * 4;
                float4 wa = *((const float4*)(wp));
                float4 wbv = *((const float4*)(wp + 32));
                float4 wc = *((const float4*)(wp + 64));
                float4 wd = *((const float4*)(wp + 96));
                r00 += q0.x * wa.x; r01 += q0.x * wa.y; r02 += q0.x * wa.z; r03 += q0.x * wa.w;
                r00 += q0.y * wbv.x; r01 += q0.y * wbv.y; r02 += q0.y * wbv.z; r03 += q0.y * wbv.w;
                r00 += q0.z * wc.x; r01 += q0.z * wc.y; r02 += q0.z * wc.z; r03 += q0.z * wc.w;
                r00 += q0.w * wd.x; r01 += q0.w * wd.y; r02 += q0.w * wd.z; r03 += q0.w * wd.w;
                r10 += q1.x * wa.x; r11 += q1.x * wa.y; r12 += q1.x * wa.z; r13 += q1.x * wa.w;
                r10 += q1.y * wbv.x; r11 += q1.y * wbv.y; r12 += q1.y * wbv.z; r13 += q1.y * wbv.w;
                r10 += q1.z * wc.x; r11 += q1.z * wc.y; r12 += q1.z * wc.z; r13 += q1.z * wc.w;
                r10 += q1.w * wd.x; r11 += q1.w * wd.y; r12 += q1.w * wd.z; r13 += q1.w * wd.w;
            }
            if (u0 != INV) {
                float* ap = acc + (int)(u0 >> 24) * 44 + coq * 4;
                __hip_atomic_fetch_add(ap + 0, r00, __ATOMIC_RELAXED, __HIP_MEMORY_SCOPE_WORKGROUP);
                __hip_atomic_fetch_add(ap + 1, r01, __ATOMIC_RELAXED, __HIP_MEMORY_SCOPE_WORKGROUP);
                __hip_atomic_fetch_add(ap + 2, r02, __ATOMIC_RELAXED, __HIP_MEMORY_SCOPE_WORKGROUP);
                __hip_atomic_fetch_add(ap + 3, r03, __ATOMIC_RELAXED, __HIP_MEMORY_SCOPE_WORKGROUP);
            }
            if (u1 != INV) {
                float* ap = acc + (int)(u1 >> 24) * 44 + coq * 4;
                __hip_atomic_fetch_add(ap + 0, r10, __ATOMIC_RELAXED, __HIP_MEMORY_SCOPE_WORKGROUP);
                __hip_atomic_fetch_add(ap + 1, r11, __ATOMIC_RELAXED, __HIP_MEMORY_SCOPE_WORKGROUP);
                __hip_atomic_fetch_add(ap + 2, r12, __ATOMIC_RELAXED, __HIP_MEMORY_SCOPE_WORKGROUP);
                __hip_atomic_fetch_add(ap + 3, r13, __ATOMIC_RELAXED, __HIP_MEMORY_SCOPE_WORKGROUP);
            }
            u0 = nu0; u1 = nu1; g0 = n0; g1 = n1;
        }
    }
    __syncthreads();
    // epilogue: 64 rows x 8 quads = 512 cells over 256 threads
    for (int cell = t; cell < 512; cell += 256) {
        int r = cell >> 3, q = cell & 7;
        int gi = (c << 6) + r;
        if (gi < count) {
            float4 o = *((const float4*)(acc + r * 44 + q * 4));
            float4 b = ((const float4*)bias)[q];
            o.x += b.x; o.y += b.y; o.z += b.z; o.w += b.w;
            int m = list[gi];
            if (ADD) {
                float4 a = ((const float4*)(addsrc + (long)m * CH))[q];
                o.x += a.x; o.y += a.y; o.z += a.z; o.w += a.w;
            }
            if (RELU) {
                o.x = fmaxf(o.x, 0.f); o.y = fmaxf(o.y, 0.f);
                o.z = fmaxf(o.z, 0.f); o.w = fmaxf(o.w, 0.f);
            }
            ((float4*)(out + (long)m * CH))[q] = o;
        }
    }
}

// ---------------- generative transpose conv k2 s2 ----------------

__global__ __launch_bounds__(256) void k_tconv(
    const float* __restrict__ h,
    const float* __restrict__ wt,
    const float* __restrict__ bt,
    float* __restrict__ out)
{
    __shared__ float wl[8 * 1060];
    for (int i = threadIdx.x; i < 8 * CH * CH; i += 256) {
        wl[(i >> 10) * 1060 + (i & 1023)] = wt[i];
    }
    __syncthreads();
    const int m = blockIdx.x * 256 + threadIdx.x;
    const int p = m >> 3, o = m & 7;
    float hr[CH], acc[CH];
    #pragma unroll
    for (int c4 = 0; c4 < 8; ++c4) {
        float4 v = ((const float4*)(h + (long)p * CH))[c4];
        hr[c4*4+0] = v.x; hr[c4*4+1] = v.y; hr[c4*4+2] = v.z; hr[c4*4+3] = v.w;
        float4 b = ((const float4*)bt)[c4];
        acc[c4*4+0] = b.x; acc[c4*4+1] = b.y; acc[c4*4+2] = b.z; acc[c4*4+3] = b.w;
    }
    const float* wb = wl + o * 1060;
    #pragma unroll
    for (int ci = 0; ci < CH; ++ci) {
        float hv = hr[ci];
        #pragma unroll
        for (int c4 = 0; c4 < 8; ++c4) {
            float4 w = *((const float4*)(wb + ci * CH + c4 * 4));
            acc[c4*4+0] += hv * w.x; acc[c4*4+1] += hv * w.y;
            acc[c4*4+2] += hv * w.z; acc[c4*4+3] += hv * w.w;
        }
    }
    #pragma unroll
    for (int c4 = 0; c4 < 8; ++c4) {
        ((float4*)(out + (long)m * CH))[c4] =
            make_float4(acc[c4*4+0], acc[c4*4+1], acc[c4*4+2], acc[c4*4+3]);
    }
}

// ---------------- classifier ----------------

__global__ __launch_bounds__(256) void k_classifier(
    const float* __restrict__ HS,
    const float* __restrict__ cw0, const float* __restrict__ cb0,
    const float* __restrict__ cw1, const float* __restrict__ cb1,
    const float* __restrict__ cw2, const float* __restrict__ cb2,
    float* __restrict__ outp, int so)
{
    __shared__ float w0[1024], w1[1024], w2[32], b0[32], b1[32];
    for (int i = threadIdx.x; i < 1024; i += 256) { w0[i] = cw0[i]; w1[i] = cw1[i]; }
    if (threadIdx.x < 32) {
        w2[threadIdx.x] = cw2[threadIdx.x];
        b0[threadIdx.x] = cb0[threadIdx.x];
        b1[threadIdx.x] = cb1[threadIdx.x];
    }
    __syncthreads();
    const int m = blockIdx.x * 256 + threadIdx.x;
    if (m >= M_ALL) return;
    if ((m & 7) != so) { outp[m] = 0.f; return; }
    float in[CH], h0[CH], h1[CH];
    #pragma unroll
    for (int c4 = 0; c4 < 8; ++c4) {
        float4 v = ((const float4*)(HS + (long)m * CH))[c4];
        in[c4*4+0] = v.x; in[c4*4+1] = v.y; in[c4*4+2] = v.z; in[c4*4+3] = v.w;
    }
    #pragma unroll
    for (int c = 0; c < CH; ++c) h0[c] = b0[c];
    #pragma unroll
    for (int ci = 0; ci < CH; ++ci) {
        float v = in[ci];
        #pragma unroll
        for (int c4 = 0; c4 < 8; ++c4) {
            float4 w = *((const float4*)(w0 + ci * CH + c4 * 4));
            h0[c4*4+0] += v * w.x; h0[c4*4+1] += v * w.y;
            h0[c4*4+2] += v * w.z; h0[c4*4+3] += v * w.w;
        }
    }
    #pragma unroll
    for (int c = 0; c < CH; ++c) { h0[c] = fmaxf(h0[c], 0.f); h1[c] = b1[c]; }
    #pragma unroll
    for (int ci = 0; ci < CH; ++ci) {
        float v = h0[ci];
        #pragma unroll
        for (int c4 = 0; c4 < 8; ++c4) {
            float4 w = *((const float4*)(w1 + ci * CH + c4 * 4));
            h1[c4*4+0] += v * w.x; h1[c4*4+1] += v * w.y;
            h1[c4*4+2] += v * w.z; h1[c4*4+3] += v * w.w;
        }
    }
    float o = cb2[0];
    #pragma unroll
    for (int ci = 0; ci < CH; ++ci) o += fmaxf(h1[ci], 0.f) * w2[ci];
    outp[m] = o;
}

// ---------------- host orchestration ----------------

extern "C" void kernel_launch(void* const* d_in, const int* in_sizes, int n_in,
                              void* d_out, int out_size, void* d_ws, size_t ws_size,
                              hipStream_t stream)
{
    (void)in_sizes; (void)n_in; (void)out_size; (void)ws_size;
    const float* x_low  = (const float*)d_in[0];
    const float* bi_w0  = (const float*)d_in[1];
    const float* bi_b0  = (const float*)d_in[2];
    const float* bi_w   = (const float*)d_in[3];
    const float* bi_b   = (const float*)d_in[4];
    const float* wt     = (const float*)d_in[5];
    const float* bt     = (const float*)d_in[6];
    const float* sw     = (const float*)d_in[7];
    const float* sb     = (const float*)d_in[8];
    const float* cw0    = (const float*)d_in[9];
    const float* cb0    = (const float*)d_in[10];
    const float* cw1    = (const float*)d_in[11];
    const float* cb1    = (const float*)d_in[12];
    const float* cw2    = (const float*)d_in[13];
    const float* cb2    = (const float*)d_in[14];
    const int* nbr_low  = (const int*)d_in[15];
    const int* nbr_u    = (const int*)d_in[16];
    const unsigned char* gtraw = (const unsigned char*)d_in[18];
    float* out = (float*)d_out;

    char* w = (char*)d_ws;
    size_t off = 0;
    auto carve = [&](size_t bytes) -> void* {
        void* p = w + off;
        off += (bytes + 255) & ~(size_t)255;
        return p;
    };
    float* feats = (float*)carve((size_t)M_ALL * CH * 4);
    float* A     = (float*)carve((size_t)M_ALL * CH * 4);
    float* X     = (float*)carve((size_t)M_ALL * CH * 4);
    float* HS    = (float*)carve((size_t)M_ALL * CH * 4);
    unsigned int* pent = (unsigned int*)carve((size_t)NCHMAX * NTAP * 64 * 4);
    int* pcnt    = (int*)carve((size_t)NCHMAX * NTAP * 4);
    int* list    = (int*)carve((size_t)M_ALL * 4);
    int* list_low= (int*)carve((size_t)N_LOW * 4);
    int* bcnt    = (int*)carve(512 * 4);
    int* boff    = (int*)carve(512 * 4);
    unsigned char* valid = (unsigned char*)carve(M_ALL);
    unsigned char* gt8   = (unsigned char*)carve(M_ALL);
    int* cnt     = (int*)carve(64 * 4);

    const size_t WL = 27648;       // 27*32*32

    k_init<<<1, 64, 0, stream>>>(cnt);
    k_gt_detect<<<512, 256, 0, stream>>>(gtraw, cnt);
    k_gt_norm<<<512, 256, 0, stream>>>(gtraw, gt8, cnt);
    k_iota<<<64, 256, 0, stream>>>(list_low);

    // ---- low-resolution block (exactly 256 chunks) ----
    k_conv_low0<<<(N_LOW * CH) / 256, 256, 0, stream>>>(x_low, nbr_low, bi_w0, bi_b0, A);
    const int GL = 256;
    k_pairs2<0><<<GL, 256, 0, stream>>>(nbr_low, list_low, cnt + 8, nullptr, pcnt, pent);
    k_convs<1,0><<<GL,256,0,stream>>>(A, X, nullptr, bi_w + 0*WL, bi_b + 0*32, list_low, cnt + 8, pcnt, pent);
    k_convs<0,1><<<GL,256,0,stream>>>(X, A, A,       bi_w + 1*WL, bi_b + 1*32, list_low, cnt + 8, pcnt, pent);
    k_convs<1,0><<<GL,256,0,stream>>>(A, X, nullptr, bi_w + 2*WL, bi_b + 2*32, list_low, cnt + 8, pcnt, pent);
    k_convs<0,1><<<GL,256,0,stream>>>(X, A, A,       bi_w + 3*WL, bi_b + 3*32, list_low, cnt + 8, pcnt, pent);
    k_convs<1,0><<<GL,256,0,stream>>>(A, X, nullptr, bi_w + 4*WL, bi_b + 4*32, list_low, cnt + 8, pcnt, pent);
    k_convs<0,1><<<GL,256,0,stream>>>(X, A, A,       bi_w + 5*WL, bi_b + 5*32, list_low, cnt + 8, pcnt, pent);
    k_convs<0,0><<<GL,256,0,stream>>>(A, X, nullptr, bi_w + 6*WL, bi_b + 6*32, list_low, cnt + 8, pcnt, pent);
    k_tconv<<<512, 256, 0, stream>>>(X, wt, bt, feats);

    // ---- 8 generative stages ----
    static const int order[8] = {0, 7, 1, 6, 5, 2, 3, 4};
    for (int s = 0; s < 8; ++s) {
        const int so = order[s];
        if (s == 0) k_vcount<1><<<512,256,0,stream>>>(valid, gt8, nullptr, nullptr, nullptr, bcnt, so);
        else        k_vcount<0><<<512,256,0,stream>>>(valid, gt8, HS, feats, X, bcnt, so);
        k_scan512<<<1, 512, 0, stream>>>(bcnt, boff, cnt + s);
        k_emit<<<512, 256, 0, stream>>>(valid, boff, list);

        // stage-s valid set is a subset of the union of the first s+1 octant
        // slices -> count <= 16384*(s+1) -> chunks <= 256*(s+1)
        int GS = 256 * (s + 1);
        if (GS > NCHMAX) GS = NCHMAX;
        k_pairs2<1><<<GS, 256, 0, stream>>>(nbr_u, list, cnt + s, valid, pcnt, pent);

        const float* sws = sw + (size_t)s * 8 * WL;
        const float* sbs = sb + (size_t)s * 8 * 32;
        const float* F0  = (s == 0) ? feats : X;
        k_convs<1,0><<<GS,256,0,stream>>>(F0, A, nullptr, sws + 0*WL, sbs + 0*32, list, cnt + s, pcnt, pent);
        k_convs<1,0><<<GS,256,0,stream>>>(A,  X, nullptr, sws + 1*WL, sbs + 1*32, list, cnt + s, pcnt, pent);
        k_convs<0,1><<<GS,256,0,stream>>>(X,  A, A,       sws + 2*WL, sbs + 2*32, list, cnt + s, pcnt, pent);
        k_convs<1,0><<<GS,256,0,stream>>>(A,  X, nullptr, sws + 3*WL, sbs + 3*32, list, cnt + s, pcnt, pent);
        k_convs<0,1><<<GS,256,0,stream>>>(X,  A, A,       sws + 4*WL, sbs + 4*32, list, cnt + s, pcnt, pent);
        k_convs<1,0><<<GS,256,0,stream>>>(A,  X, nullptr, sws + 5*WL, sbs + 5*32, list, cnt + s, pcnt, pent);
        k_convs<0,1><<<GS,256,0,stream>>>(X,  A, A,       sws + 6*WL, sbs + 6*32, list, cnt + s, pcnt, pent);
        k_convs<0,0><<<GS,256,0,stream>>>(A, HS, nullptr, sws + 7*WL, sbs + 7*32, list, cnt + s, pcnt, pent);

        k_classifier<<<512,256,0,stream>>>(HS, cw0, cb0, cw1, cb1, cw2, cb2,
                                           out + (size_t)s * M_ALL, so);
    }
}

// Round 9
// 8770.930 us; speedup vs baseline: 1.6980x; 1.6980x over previous
//
#include <hip/hip_runtime.h>
#include <cstdint>

#define NTAP 27
#define CH 32
static constexpr int N_LOW = 16384;
static constexpr int M_ALL = 131072;
static constexpr int NCHMAX = 2048;   // hard bound: M_ALL/64 chunks

// ---------------- init / gt_mask normalization ----------------

__global__ void k_init(int* cnt) {
    int t = threadIdx.x;
    if (t < 64) cnt[t] = 0;
    if (t == 0) cnt[8] = N_LOW;     // low-map row count
}

__global__ __launch_bounds__(256) void k_gt_detect(const unsigned char* __restrict__ p, int* flags) {
    int i = blockIdx.x * 256 + threadIdx.x;
    bool a = false, b = false;
    if (i < M_ALL) {
        unsigned char v = p[i];
        a = ((i & 3) != 0) && (v != 0);
        b = (v > 1);
    }
    unsigned long long ba = __ballot(a);
    unsigned long long bb = __ballot(b);
    if ((threadIdx.x & 63) == 0) {
        if (ba) atomicOr(&flags[32], 1);
        if (bb) atomicOr(&flags[33], 1);
    }
}

__global__ __launch_bounds__(256) void k_gt_norm(const unsigned char* __restrict__ p,
                                                 unsigned char* __restrict__ gt8,
                                                 const int* __restrict__ flags) {
    int i = blockIdx.x * 256 + threadIdx.x;
    if (i >= M_ALL) return;
    bool u8 = (flags[32] != 0) && (flags[33] == 0);
    unsigned char v;
    if (u8) v = (p[i] != 0) ? 1 : 0;
    else    v = (((const int*)p)[i] != 0) ? 1 : 0;
    gt8[i] = v;
}

__global__ __launch_bounds__(256) void k_iota(int* list) {
    int i = blockIdx.x * 256 + threadIdx.x;
    if (i < N_LOW) list[i] = i;
}

// ---------------- low-grid first conv (Cin=1) ----------------

__global__ __launch_bounds__(256) void k_conv_low0(const float* __restrict__ x,
                                                   const int* __restrict__ nbr,
                                                   const float* __restrict__ w0,
                                                   const float* __restrict__ b0,
                                                   float* __restrict__ out) {
    int g = blockIdx.x * 256 + threadIdx.x;
    int n = g >> 5, co = g & 31;
    float acc = b0[co];
    const int* nr = nbr + n * NTAP;
    for (int k = 0; k < NTAP; ++k) {
        int j = nr[k];
        if (j >= 0) acc += x[j] * w0[k * CH + co];
    }
    out[g] = fmaxf(acc, 0.f);
}

// ---------------- ordered compaction (count / scan / emit) ----------------

template<int FIRST>
__global__ __launch_bounds__(256) void k_vcount(unsigned char* __restrict__ valid,
                                                const unsigned char* __restrict__ gt8,
                                                const float* __restrict__ HS,
                                                const float* __restrict__ feats,
                                                float* __restrict__ F,
                                                int* __restrict__ bcnt, int so) {
    int m = blockIdx.x * 256 + threadIdx.x;
    int v;
    if (FIRST) {
        v = ((m & 7) == 0);
    } else {
        int ov = valid[m] & gt8[m];
        int sl = ((m & 7) == so);
        v = ov | sl;
        if (v) {
            const float4* src = (const float4*)((ov ? HS : feats) + (long)m * CH);
            float4* dst = (float4*)(F + (long)m * CH);
            #pragma unroll
            for (int i = 0; i < 8; ++i) dst[i] = src[i];
        }
    }
    valid[m] = (unsigned char)v;
    __shared__ int red[4];
    unsigned long long b = __ballot(v != 0);
    if ((threadIdx.x & 63) == 0) red[threadIdx.x >> 6] = __popcll(b);
    __syncthreads();
    if (threadIdx.x == 0) bcnt[blockIdx.x] = red[0] + red[1] + red[2] + red[3];
}

__global__ void k_scan512(const int* __restrict__ bcnt, int* __restrict__ boff,
                          int* __restrict__ cnt_out) {
    __shared__ int s[512];
    int t = threadIdx.x;
    int mine = bcnt[t];
    s[t] = mine;
    __syncthreads();
    for (int d = 1; d < 512; d <<= 1) {
        int v = (t >= d) ? s[t - d] : 0;
        __syncthreads();
        s[t] += v;
        __syncthreads();
    }
    boff[t] = s[t] - mine;
    if (t == 511) cnt_out[0] = s[511];
}

__global__ __launch_bounds__(256) void k_emit(const unsigned char* __restrict__ valid,
                                              const int* __restrict__ boff,
                                              int* __restrict__ list) {
    int m = blockIdx.x * 256 + threadIdx.x;
    int v = valid[m];
    __shared__ int wof[4];
    unsigned long long b = __ballot(v != 0);
    int lane = threadIdx.x & 63, w = threadIdx.x >> 6;
    int rank = __popcll(b & ((1ull << lane) - 1ull));
    if (lane == 0) wof[w] = __popcll(b);
    __syncthreads();
    int pre = 0;
    for (int i = 0; i < w; ++i) pre += wof[i];
    if (v) list[boff[blockIdx.x] + pre + rank] = m;
}

// ---------------- pair-list build per (chunk, tap): ballot-based, no atomics --------
// pent[(c*27+k)*64 + rank] = (lrow<<24) | j ; pcnt[c*27+k] = popcount.

template<int VAL>
__global__ __launch_bounds__(256) void k_pairs2(const int* __restrict__ nbr,
                                                const int* __restrict__ list,
                                                const int* __restrict__ d_count,
                                                const unsigned char* __restrict__ valid,
                                                int* __restrict__ pcnt,
                                                unsigned int* __restrict__ pent) {
    const int count = d_count[0];
    const int nch = (count + 63) >> 6;
    const int c = blockIdx.x;
    if (c >= nch) return;
    const int t = threadIdx.x, wave = t >> 6, lane = t & 63;
    const int gi = (c << 6) + lane;
    const int m = (gi < count) ? list[gi] : -1;
    const int* nr = nbr + (long)m * NTAP;
    for (int k = wave; k < NTAP; k += 4) {
        int j = -1;
        if (m >= 0) {
            j = nr[k];
            if (VAL && j >= 0 && !valid[j]) j = -1;
        }
        unsigned long long mask = __ballot(j >= 0);
        int rank = __popcll(mask & ((1ull << lane) - 1ull));
        if (j >= 0)
            pent[(((long)(c * NTAP + k)) << 6) | rank] = ((unsigned)lane << 24) | (unsigned)j;
        if (lane == 0) pcnt[c * NTAP + k] = __popcll(mask);
    }
}

// ---- pair-compacted conv (R4 structure, 4-pair inner block): 4 waves split taps,
// ---- wave-private acc planes; batch = 32 entries (4 pairs/slot) to amortize W reads.

#define INV 0xFFFFFFFFu

template<int RELU, int ADD>
__global__ __launch_bounds__(256, 2) void k_convp(
    const float* __restrict__ f,
    float* __restrict__ out,
    const float* __restrict__ addsrc,
    const float* __restrict__ W,        // [27][32][32]
    const float* __restrict__ bias,     // [32]
    const int* __restrict__ list,
    const int* __restrict__ d_count,
    const int* __restrict__ pcnt,
    const unsigned int* __restrict__ pent)
{
    __shared__ float acc[4 * 64 * 36];   // 36864 B: wave-private planes, stride-36
    __shared__ float wb[4 * 1024];       // 16384 B: wave-private W[k]
    __shared__ float fb[4 * 8 * 144];    // 18432 B: wave-private, 8 slots x 4 pairs x 36
    const int count = d_count[0];
    const int nch = (count + 63) >> 6;
    const int c = blockIdx.x;
    if (c >= nch) return;
    const int t = threadIdx.x;
    const int wave = t >> 6, lane = t & 63;
    const int slot = lane >> 3, coq = lane & 7;
    const float4 z4 = make_float4(0.f, 0.f, 0.f, 0.f);
    for (int i = t; i < 2304; i += 256) ((float4*)acc)[i] = z4;
    __syncthreads();
    float* accw = acc + wave * 2304;
    float* wbw = wb + wave * 1024;
    float* fbw = fb + wave * 1152;
    const int base_ck = c * NTAP;

    for (int k = wave; k < NTAP; k += 4) {
        const int L = pcnt[base_ck + k];
        if (L == 0) continue;
        // stage W[k] (wave-local, contiguous)
        const float4* Wg = (const float4*)(W + (long)k * 1024);
        #pragma unroll
        for (int r = 0; r < 4; ++r)
            *((float4*)(wbw + (lane + 64 * r) * 4)) = Wg[lane + 64 * r];
        const unsigned int* pk = pent + (((long)(base_ck + k)) << 6);
        // preload this slot's entries: batch b uses ent[4b+p]
        unsigned ent[8];
        #pragma unroll
        for (int r = 0; r < 8; ++r) {
            int idx = r * 8 + slot;
            ent[r] = (idx < L) ? pk[idx] : INV;
        }
        const int nb = (L + 31) >> 5;   // 1 or 2 super-batches of 32 entries
        // prefetch batch 0 gathers
        unsigned u0 = ent[0], u1 = ent[1], u2 = ent[2], u3 = ent[3];
        float4 g0 = z4, g1 = z4, g2 = z4, g3 = z4;
        if (u0 != INV) g0 = ((const float4*)(f + (long)(u0 & 0xFFFFFFu) * CH))[coq];
        if (u1 != INV) g1 = ((const float4*)(f + (long)(u1 & 0xFFFFFFu) * CH))[coq];
        if (u2 != INV) g2 = ((const float4*)(f + (long)(u2 & 0xFFFFFFu) * CH))[coq];
        if (u3 != INV) g3 = ((const float4*)(f + (long)(u3 & 0xFFFFFFu) * CH))[coq];
        #pragma unroll
        for (int b = 0; b < 2; ++b) {
            if (b >= nb) break;
            // stage current super-batch (compiler inserts vmcnt wait on g*)
            *((float4*)(fbw + slot * 144 +   0 + coq * 4)) = g0;
            *((float4*)(fbw + slot * 144 +  36 + coq * 4)) = g1;
            *((float4*)(fbw + slot * 144 +  72 + coq * 4)) = g2;
            *((float4*)(fbw + slot * 144 + 108 + coq * 4)) = g3;
            // issue next super-batch's gathers (overlap with FMA below)
            unsigned nu0 = INV, nu1 = INV, nu2 = INV, nu3 = INV;
            float4 n0 = z4, n1 = z4, n2 = z4, n3 = z4;
            if (b == 0 && nb > 1) {
                nu0 = ent[4]; nu1 = ent[5]; nu2 = ent[6]; nu3 = ent[7];
                if (nu0 != INV) n0 = ((const float4*)(f + (long)(nu0 & 0xFFFFFFu) * CH))[coq];
                if (nu1 != INV) n1 = ((const float4*)(f + (long)(nu1 & 0xFFFFFFu) * CH))[coq];
                if (nu2 != INV) n2 = ((const float4*)(f + (long)(nu2 & 0xFFFFFFu) * CH))[coq];
                if (nu3 != INV) n3 = ((const float4*)(f + (long)(nu3 & 0xFFFFFFu) * CH))[coq];
            }
            asm volatile("s_waitcnt lgkmcnt(0)" ::: "memory");
            __builtin_amdgcn_sched_barrier(0);
            float4 a0 = z4, a1 = z4, a2 = z4, a3 = z4;
            #pragma unroll
            for (int c4 = 0; c4 < 8; ++c4) {
                float4 q0 = *((const float4*)(fbw + slot * 144 +   0 + c4 * 4));
                float4 q1 = *((const float4*)(fbw + slot * 144 +  36 + c4 * 4));
                float4 q2 = *((const float4*)(fbw + slot * 144 +  72 + c4 * 4));
                float4 q3 = *((const float4*)(fbw + slot * 144 + 108 + c4 * 4));
                const float* wp = wbw + c4 * 128 + coq * 4;
                float4 wa = *((const float4*)(wp));
                float4 wv = *((const float4*)(wp + 32));
                float4 wc = *((const float4*)(wp + 64));
                float4 wd = *((const float4*)(wp + 96));
                a0.x += q0.x * wa.x + q0.y * wv.x + q0.z * wc.x + q0.w * wd.x;
                a0.y += q0.x * wa.y + q0.y * wv.y + q0.z * wc.y + q0.w * wd.y;
                a0.z += q0.x * wa.z + q0.y * wv.z + q0.z * wc.z + q0.w * wd.z;
                a0.w += q0.x * wa.w + q0.y * wv.w + q0.z * wc.w + q0.w * wd.w;
                a1.x += q1.x * wa.x + q1.y * wv.x + q1.z * wc.x + q1.w * wd.x;
                a1.y += q1.x * wa.y + q1.y * wv.y + q1.z * wc.y + q1.w * wd.y;
                a1.z += q1.x * wa.z + q1.y * wv.z + q1.z * wc.z + q1.w * wd.z;
                a1.w += q1.x * wa.w + q1.y * wv.w + q1.z * wc.w + q1.w * wd.w;
                a2.x += q2.x * wa.x + q2.y * wv.x + q2.z * wc.x + q2.w * wd.x;
                a2.y += q2.x * wa.y + q2.y * wv.y + q2.z * wc.y + q2.w * wd.y;
                a2.z += q2.x * wa.z + q2.y * wv.z + q2.z * wc.z + q2.w * wd.z;
                a2.w += q2.x * wa.w + q2.y * wv.w + q2.z * wc.w + q2.w * wd.w;
                a3.x += q3.x * wa.x + q3.y * wv.x + q3.z * wc.x + q3.w * wd.x;
                a3.y += q3.x * wa.y + q3.y * wv.y + q3.z * wc.y + q3.w * wd.y;
                a3.z += q3.x * wa.z + q3.y * wv.z + q3.z * wc.z + q3.w * wd.z;
                a3.w += q3.x * wa.w + q3.y * wv.w + q3.z * wc.w + q3.w * wd.w;
            }
            if (u0 != INV) {
                float4* ap = (float4*)(accw + (int)(u0 >> 24) * 36 + coq * 4);
                float4 av = *ap;
                av.x += a0.x; av.y += a0.y; av.z += a0.z; av.w += a0.w;
                *ap = av;
            }
            if (u1 != INV) {
                float4* ap = (float4*)(accw + (int)(u1 >> 24) * 36 + coq * 4);
                float4 av = *ap;
                av.x += a1.x; av.y += a1.y; av.z += a1.z; av.w += a1.w;
                *ap = av;
            }
            if (u2 != INV) {
                float4* ap = (float4*)(accw + (int)(u2 >> 24) * 36 + coq * 4);
                float4 av = *ap;
                av.x += a2.x; av.y += a2.y; av.z += a2.z; av.w += a2.w;
                *ap = av;
            }
            if (u3 != INV) {
                float4* ap = (float4*)(accw + (int)(u3 >> 24) * 36 + coq * 4);
                float4 av = *ap;
                av.x += a3.x; av.y += a3.y; av.z += a3.z; av.w += a3.w;
                *ap = av;
            }
            u0 = nu0; u1 = nu1; u2 = nu2; u3 = nu3;
            g0 = n0; g1 = n1; g2 = n2; g3 = n3;
        }
    }
    __syncthreads();
    // reduce 4 wave planes + epilogue
    for (int cell = t; cell < 512; cell += 256) {
        int r = cell >> 3, q = cell & 7;
        int gi = (c << 6) + r;
        if (gi < count) {
            const int ro = r * 36 + q * 4;
            float4 s0 = *((const float4*)(acc + 0 * 2304 + ro));
            float4 s1 = *((const float4*)(acc + 1 * 2304 + ro));
            float4 s2 = *((const float4*)(acc + 2 * 2304 + ro));
            float4 s3 = *((const float4*)(acc + 3 * 2304 + ro));
            float4 b = ((const float4*)bias)[q];
            float4 o;
            o.x = s0.x + s1.x + s2.x + s3.x + b.x;
            o.y = s0.y + s1.y + s2.y + s3.y + b.y;
            o.z = s0.z + s1.z + s2.z + s3.z + b.z;
            o.w = s0.w + s1.w + s2.w + s3.w + b.w;
            int m = list[gi];
            if (ADD) {
                float4 a = ((const float4*)(addsrc + (long)m * CH))[q];
                o.x += a.x; o.y += a.y; o.z += a.z; o.w += a.w;
            }
            if (RELU) {
                o.x = fmaxf(o.x, 0.f); o.y = fmaxf(o.y, 0.f);
                o.z = fmaxf(o.z, 0.f); o.w = fmaxf(o.w, 0.f);
            }
            ((float4*)(out + (long)m * CH))[q] = o;
        }
    }
}

// ---------------- generative transpose conv k2 s2 ----------------

__global__ __launch_bounds__(256) void k_tconv(
    const float* __restrict__ h,
    const float* __restrict__ wt,
    const float* __restrict__ bt,
    float* __restrict__ out)
{
    __shared__ float wl[8 * 1060];
    for (int i = threadIdx.x; i < 8 * CH * CH; i += 256) {
        wl[(i >> 10) * 1060 + (i & 1023)] = wt[i];
    }
    __syncthreads();
    const int m = blockIdx.x * 256 + threadIdx.x;
    const int p = m >> 3, o = m & 7;
    float hr[CH], acc[CH];
    #pragma unroll
    for (int c4 = 0; c4 < 8; ++c4) {
        float4 v = ((const float4*)(h + (long)p * CH))[c4];
        hr[c4*4+0] = v.x; hr[c4*4+1] = v.y; hr[c4*4+2] = v.z; hr[c4*4+3] = v.w;
        float4 b = ((const float4*)bt)[c4];
        acc[c4*4+0] = b.x; acc[c4*4+1] = b.y; acc[c4*4+2] = b.z; acc[c4*4+3] = b.w;
    }
    const float* wb = wl + o * 1060;
    #pragma unroll
    for (int ci = 0; ci < CH; ++ci) {
        float hv = hr[ci];
        #pragma unroll
        for (int c4 = 0; c4 < 8; ++c4) {
            float4 w = *((const float4*)(wb + ci * CH + c4 * 4));
            acc[c4*4+0] += hv * w.x; acc[c4*4+1] += hv * w.y;
            acc[c4*4+2] += hv * w.z; acc[c4*4+3] += hv * w.w;
        }
    }
    #pragma unroll
    for (int c4 = 0; c4 < 8; ++c4) {
        ((float4*)(out + (long)m * CH))[c4] =
            make_float4(acc[c4*4+0], acc[c4*4+1], acc[c4*4+2], acc[c4*4+3]);
    }
}

// ---------------- classifier ----------------

__global__ __launch_bounds__(256) void k_classifier(
    const float* __restrict__ HS,
    const float* __restrict__ cw0, const float* __restrict__ cb0,
    const float* __restrict__ cw1, const float* __restrict__ cb1,
    const float* __restrict__ cw2, const float* __restrict__ cb2,
    float* __restrict__ outp, int so)
{
    __shared__ float w0[1024], w1[1024], w2[32], b0[32], b1[32];
    for (int i = threadIdx.x; i < 1024; i += 256) { w0[i] = cw0[i]; w1[i] = cw1[i]; }
    if (threadIdx.x < 32) {
        w2[threadIdx.x] = cw2[threadIdx.x];
        b0[threadIdx.x] = cb0[threadIdx.x];
        b1[threadIdx.x] = cb1[threadIdx.x];
    }
    __syncthreads();
    const int m = blockIdx.x * 256 + threadIdx.x;
    if (m >= M_ALL) return;
    if ((m & 7) != so) { outp[m] = 0.f; return; }
    float in[CH], h0[CH], h1[CH];
    #pragma unroll
    for (int c4 = 0; c4 < 8; ++c4) {
        float4 v = ((const float4*)(HS + (long)m * CH))[c4];
        in[c4*4+0] = v.x; in[c4*4+1] = v.y; in[c4*4+2] = v.z; in[c4*4+3] = v.w;
    }
    #pragma unroll
    for (int c = 0; c < CH; ++c) h0[c] = b0[c];
    #pragma unroll
    for (int ci = 0; ci < CH; ++ci) {
        float v = in[ci];
        #pragma unroll
        for (int c4 = 0; c4 < 8; ++c4) {
            float4 w = *((const float4*)(w0 + ci * CH + c4 * 4));
            h0[c4*4+0] += v * w.x; h0[c4*4+1] += v * w.y;
            h0[c4*4+2] += v * w.z; h0[c4*4+3] += v * w.w;
        }
    }
    #pragma unroll
    for (int c = 0; c < CH; ++c) { h0[c] = fmaxf(h0[c], 0.f); h1[c] = b1[c]; }
    #pragma unroll
    for (int ci = 0; ci < CH; ++ci) {
        float v = h0[ci];
        #pragma unroll
        for (int c4 = 0; c4 < 8; ++c4) {
            float4 w = *((const float4*)(w1 + ci * CH + c4 * 4));
            h1[c4*4+0] += v * w.x; h1[c4*4+1] += v * w.y;
            h1[c4*4+2] += v * w.z; h1[c4*4+3] += v * w.w;
        }
    }
    float o = cb2[0];
    #pragma unroll
    for (int ci = 0; ci < CH; ++ci) o += fmaxf(h1[ci], 0.f) * w2[ci];
    outp[m] = o;
}

// ---------------- host orchestration ----------------

extern "C" void kernel_launch(void* const* d_in, const int* in_sizes, int n_in,
                              void* d_out, int out_size, void* d_ws, size_t ws_size,
                              hipStream_t stream)
{
    (void)in_sizes; (void)n_in; (void)out_size; (void)ws_size;
    const float* x_low  = (const float*)d_in[0];
    const float* bi_w0  = (const float*)d_in[1];
    const float* bi_b0  = (const float*)d_in[2];
    const float* bi_w   = (const float*)d_in[3];
    const float* bi_b   = (const float*)d_in[4];
    const float* wt     = (const float*)d_in[5];
    const float* bt     = (const float*)d_in[6];
    const float* sw     = (const float*)d_in[7];
    const float* sb     = (const float*)d_in[8];
    const float* cw0    = (const float*)d_in[9];
    const float* cb0    = (const float*)d_in[10];
    const float* cw1    = (const float*)d_in[11];
    const float* cb1    = (const float*)d_in[12];
    const float* cw2    = (const float*)d_in[13];
    const float* cb2    = (const float*)d_in[14];
    const int* nbr_low  = (const int*)d_in[15];
    const int* nbr_u    = (const int*)d_in[16];
    const unsigned char* gtraw = (const unsigned char*)d_in[18];
    float* out = (float*)d_out;

    char* w = (char*)d_ws;
    size_t off = 0;
    auto carve = [&](size_t bytes) -> void* {
        void* p = w + off;
        off += (bytes + 255) & ~(size_t)255;
        return p;
    };
    float* feats = (float*)carve((size_t)M_ALL * CH * 4);
    float* A     = (float*)carve((size_t)M_ALL * CH * 4);
    float* X     = (float*)carve((size_t)M_ALL * CH * 4);
    float* HS    = (float*)carve((size_t)M_ALL * CH * 4);
    unsigned int* pent = (unsigned int*)carve((size_t)NCHMAX * NTAP * 64 * 4);
    int* pcnt    = (int*)carve((size_t)NCHMAX * NTAP * 4);
    int* list    = (int*)carve((size_t)M_ALL * 4);
    int* list_low= (int*)carve((size_t)N_LOW * 4);
    int* bcnt    = (int*)carve(512 * 4);
    int* boff    = (int*)carve(512 * 4);
    unsigned char* valid = (unsigned char*)carve(M_ALL);
    unsigned char* gt8   = (unsigned char*)carve(M_ALL);
    int* cnt     = (int*)carve(64 * 4);

    const size_t WL = 27648;       // 27*32*32

    k_init<<<1, 64, 0, stream>>>(cnt);
    k_gt_detect<<<512, 256, 0, stream>>>(gtraw, cnt);
    k_gt_norm<<<512, 256, 0, stream>>>(gtraw, gt8, cnt);
    k_iota<<<64, 256, 0, stream>>>(list_low);

    // ---- low-resolution block (exactly 256 chunks) ----
    k_conv_low0<<<(N_LOW * CH) / 256, 256, 0, stream>>>(x_low, nbr_low, bi_w0, bi_b0, A);
    const int GL = 256;
    k_pairs2<0><<<GL, 256, 0, stream>>>(nbr_low, list_low, cnt + 8, nullptr, pcnt, pent);
    k_convp<1,0><<<GL,256,0,stream>>>(A, X, nullptr, bi_w + 0*WL, bi_b + 0*32, list_low, cnt + 8, pcnt, pent);
    k_convp<0,1><<<GL,256,0,stream>>>(X, A, A,       bi_w + 1*WL, bi_b + 1*32, list_low, cnt + 8, pcnt, pent);
    k_convp<1,0><<<GL,256,0,stream>>>(A, X, nullptr, bi_w + 2*WL, bi_b + 2*32, list_low, cnt + 8, pcnt, pent);
    k_convp<0,1><<<GL,256,0,stream>>>(X, A, A,       bi_w + 3*WL, bi_b + 3*32, list_low, cnt + 8, pcnt, pent);
    k_convp<1,0><<<GL,256,0,stream>>>(A, X, nullptr, bi_w + 4*WL, bi_b + 4*32, list_low, cnt + 8, pcnt, pent);
    k_convp<0,1><<<GL,256,0,stream>>>(X, A, A,       bi_w + 5*WL, bi_b + 5*32, list_low, cnt + 8, pcnt, pent);
    k_convp<0,0><<<GL,256,0,stream>>>(A, X, nullptr, bi_w + 6*WL, bi_b + 6*32, list_low, cnt + 8, pcnt, pent);
    k_tconv<<<512, 256, 0, stream>>>(X, wt, bt, feats);

    // ---- 8 generative stages ----
    static const int order[8] = {0, 7, 1, 6, 5, 2, 3, 4};
    for (int s = 0; s < 8; ++s) {
        const int so = order[s];
        if (s == 0) k_vcount<1><<<512,256,0,stream>>>(valid, gt8, nullptr, nullptr, nullptr, bcnt, so);
        else        k_vcount<0><<<512,256,0,stream>>>(valid, gt8, HS, feats, X, bcnt, so);
        k_scan512<<<1, 512, 0, stream>>>(bcnt, boff, cnt + s);
        k_emit<<<512, 256, 0, stream>>>(valid, boff, list);

        // stage-s valid set is a subset of the union of the first s+1 octant
        // slices -> count <= 16384*(s+1) -> chunks <= 256*(s+1)
        int GS = 256 * (s + 1);
        if (GS > NCHMAX) GS = NCHMAX;
        k_pairs2<1><<<GS, 256, 0, stream>>>(nbr_u, list, cnt + s, valid, pcnt, pent);

        const float* sws = sw + (size_t)s * 8 * WL;
        const float* sbs = sb + (size_t)s * 8 * 32;
        const float* F0  = (s == 0) ? feats : X;
        k_convp<1,0><<<GS,256,0,stream>>>(F0, A, nullptr, sws + 0*WL, sbs + 0*32, list, cnt + s, pcnt, pent);
        k_convp<1,0><<<GS,256,0,stream>>>(A,  X, nullptr, sws + 1*WL, sbs + 1*32, list, cnt + s, pcnt, pent);
        k_convp<0,1><<<GS,256,0,stream>>>(X,  A, A,       sws + 2*WL, sbs + 2*32, list, cnt + s, pcnt, pent);
        k_convp<1,0><<<GS,256,0,stream>>>(A,  X, nullptr, sws + 3*WL, sbs + 3*32, list, cnt + s, pcnt, pent);
        k_convp<0,1><<<GS,256,0,stream>>>(X,  A, A,       sws + 4*WL, sbs + 4*32, list, cnt + s, pcnt, pent);
        k_convp<1,0><<<GS,256,0,stream>>>(A,  X, nullptr, sws + 5*WL, sbs + 5*32, list, cnt + s, pcnt, pent);
        k_convp<0,1><<<GS,256,0,stream>>>(X,  A, A,       sws + 6*WL, sbs + 6*32, list, cnt + s, pcnt, pent);
        k_convp<0,0><<<GS,256,0,stream>>>(A, HS, nullptr, sws + 7*WL, sbs + 7*32, list, cnt + s, pcnt, pent);

        k_classifier<<<512,256,0,stream>>>(HS, cw0, cb0, cw1, cb1, cw2, cb2,
                                           out + (size_t)s * M_ALL, so);
    }
}

// Round 11
// 2407.606 us; speedup vs baseline: 6.1859x; 3.6430x over previous
//
#include <hip/hip_runtime.h>
#include <cstdint>

#define NTAP 27
#define CH 32
static constexpr int N_LOW = 16384;
static constexpr int M_ALL = 131072;
static constexpr int NCHMAX = 2048;   // hard bound: M_ALL/64 chunks

// ---------------- init / gt_mask normalization ----------------

__global__ void k_init(int* cnt) {
    int t = threadIdx.x;
    if (t < 64) cnt[t] = 0;
    if (t == 0) cnt[8] = N_LOW;     // low-map row count
}

__global__ __launch_bounds__(256) void k_gt_detect(const unsigned char* __restrict__ p, int* flags) {
    int i = blockIdx.x * 256 + threadIdx.x;
    bool a = false, b = false;
    if (i < M_ALL) {
        unsigned char v = p[i];
        a = ((i & 3) != 0) && (v != 0);
        b = (v > 1);
    }
    unsigned long long ba = __ballot(a);
    unsigned long long bb = __ballot(b);
    if ((threadIdx.x & 63) == 0) {
        if (ba) atomicOr(&flags[32], 1);
        if (bb) atomicOr(&flags[33], 1);
    }
}

__global__ __launch_bounds__(256) void k_gt_norm(const unsigned char* __restrict__ p,
                                                 unsigned char* __restrict__ gt8,
                                                 const int* __restrict__ flags) {
    int i = blockIdx.x * 256 + threadIdx.x;
    if (i >= M_ALL) return;
    bool u8 = (flags[32] != 0) && (flags[33] == 0);
    unsigned char v;
    if (u8) v = (p[i] != 0) ? 1 : 0;
    else    v = (((const int*)p)[i] != 0) ? 1 : 0;
    gt8[i] = v;
}

__global__ __launch_bounds__(256) void k_iota(int* list) {
    int i = blockIdx.x * 256 + threadIdx.x;
    if (i < N_LOW) list[i] = i;
}

// ---------------- low-grid first conv (Cin=1) ----------------

__global__ __launch_bounds__(256) void k_conv_low0(const float* __restrict__ x,
                                                   const int* __restrict__ nbr,
                                                   const float* __restrict__ w0,
                                                   const float* __restrict__ b0,
                                                   float* __restrict__ out) {
    int g = blockIdx.x * 256 + threadIdx.x;
    int n = g >> 5, co = g & 31;
    float acc = b0[co];
    const int* nr = nbr + n * NTAP;
    for (int k = 0; k < NTAP; ++k) {
        int j = nr[k];
        if (j >= 0) acc += x[j] * w0[k * CH + co];
    }
    out[g] = fmaxf(acc, 0.f);
}

// ------- fused compaction: valid update + F copy + ballot pack + atomic base -------
// Unordered across blocks (chunk membership varies) — numerics are row-local and
// bitwise-identical regardless of chunking: per row, taps accumulate in k-order,
// each tap contributes one batch-computed float4 sum in fixed ci order.

template<int FIRST>
__global__ __launch_bounds__(256) void k_compact(unsigned char* __restrict__ valid,
                                                 const unsigned char* __restrict__ gt8,
                                                 const float* __restrict__ HS,
                                                 const float* __restrict__ feats,
                                                 float* __restrict__ F,
                                                 int* __restrict__ list,
                                                 int* __restrict__ cnt, int so) {
    int m = blockIdx.x * 256 + threadIdx.x;
    int v;
    if (FIRST) {
        v = ((m & 7) == 0);
    } else {
        int ov = valid[m] & gt8[m];
        int sl = ((m & 7) == so);
        v = ov | sl;
        if (v) {
            const float4* src = (const float4*)((ov ? HS : feats) + (long)m * CH);
            float4* dst = (float4*)(F + (long)m * CH);
            #pragma unroll
            for (int i = 0; i < 8; ++i) dst[i] = src[i];
        }
    }
    valid[m] = (unsigned char)v;
    __shared__ int wof[4];
    __shared__ int bbase;
    unsigned long long b = __ballot(v != 0);
    int lane = threadIdx.x & 63, w = threadIdx.x >> 6;
    int rank = __popcll(b & ((1ull << lane) - 1ull));
    if (lane == 0) wof[w] = __popcll(b);
    __syncthreads();
    if (threadIdx.x == 0) {
        int c0 = wof[0], c1 = wof[1], c2 = wof[2], c3 = wof[3];
        int tot = c0 + c1 + c2 + c3;
        bbase = atomicAdd(cnt, tot);
        wof[0] = 0; wof[1] = c0; wof[2] = c0 + c1; wof[3] = c0 + c1 + c2;
    }
    __syncthreads();
    if (v) list[bbase + wof[w] + rank] = m;
}

// ---------------- pair-list build per (chunk, tap): ballot-based, no atomics --------
// pent[(c*27+k)*64 + rank] = (lrow<<24) | j ; pcnt[c*27+k] = popcount.

template<int VAL>
__global__ __launch_bounds__(256) void k_pairs2(const int* __restrict__ nbr,
                                                const int* __restrict__ list,
                                                const int* __restrict__ d_count,
                                                const unsigned char* __restrict__ valid,
                                                int* __restrict__ pcnt,
                                                unsigned int* __restrict__ pent) {
    const int count = d_count[0];
    const int nch = (count + 63) >> 6;
    const int c = blockIdx.x;
    if (c >= nch) return;
    const int t = threadIdx.x, wave = t >> 6, lane = t & 63;
    const int gi = (c << 6) + lane;
    const int m = (gi < count) ? list[gi] : -1;
    const int* nr = nbr + (long)m * NTAP;
    for (int k = wave; k < NTAP; k += 4) {
        int j = -1;
        if (m >= 0) {
            j = nr[k];
            if (VAL && j >= 0 && !valid[j]) j = -1;
        }
        unsigned long long mask = __ballot(j >= 0);
        int rank = __popcll(mask & ((1ull << lane) - 1ull));
        if (j >= 0)
            pent[(((long)(c * NTAP + k)) << 6) | rank] = ((unsigned)lane << 24) | (unsigned)j;
        if (lane == 0) pcnt[c * NTAP + k] = __popcll(mask);
    }
}

// ---------------- pair-compacted conv: 4 waves, wave-private taps+acc ----------------
// (R4-exact: 16-entry batches, 2 pairs/slot, 1-deep gather prefetch, VGPR~128)

#define INV 0xFFFFFFFFu

template<int RELU, int ADD>
__global__ __launch_bounds__(256) void k_convp(
    const float* __restrict__ f,
    float* __restrict__ out,
    const float* __restrict__ addsrc,
    const float* __restrict__ W,        // [27][32][32]
    const float* __restrict__ bias,     // [32]
    const int* __restrict__ list,
    const int* __restrict__ d_count,
    const int* __restrict__ pcnt,
    const unsigned int* __restrict__ pent)
{
    __shared__ float acc[4 * 64 * 36];   // wave-private planes, stride-36 padded
    __shared__ float wb[4 * 1024];       // wave-private W[k]
    __shared__ float fb[4 * 16 * 36];    // wave-private staged rows (2 per slot)
    const int count = d_count[0];
    const int nch = (count + 63) >> 6;
    const int c = blockIdx.x;
    if (c >= nch) return;
    const int t = threadIdx.x;
    const int wave = t >> 6, lane = t & 63;
    const int slot = lane >> 3, coq = lane & 7;
    for (int i = t; i < 4 * 64 * 36; i += 256) acc[i] = 0.f;
    __syncthreads();
    float* accw = acc + wave * (64 * 36);
    float* wbw = wb + wave * 1024;
    float* fbw = fb + wave * (16 * 36);
    const int base_ck = c * NTAP;

    for (int k = wave; k < NTAP; k += 4) {
        const int L = pcnt[base_ck + k];
        if (L == 0) continue;
        // stage W[k] (wave-local, contiguous)
        const float4* Wg = (const float4*)(W + (long)k * 1024);
        #pragma unroll
        for (int r = 0; r < 4; ++r) {
            float4 v = Wg[lane + 64 * r];
            *((float4*)(wbw + (lane + 64 * r) * 4)) = v;
        }
        const unsigned int* pk = pent + (((long)(base_ck + k)) << 6);
        // preload this slot's entries (batch b uses ent[2b], ent[2b+1])
        unsigned ent[8];
        #pragma unroll
        for (int r = 0; r < 8; ++r) {
            int idx = r * 8 + slot;
            ent[r] = (idx < L) ? pk[idx] : INV;
        }
        const int nb = (L + 15) >> 4;
        // prefetch batch 0
        unsigned u0 = ent[0], u1 = ent[1];
        float4 g0 = make_float4(0.f, 0.f, 0.f, 0.f), g1 = g0;
        if (u0 != INV) g0 = ((const float4*)(f + (long)(u0 & 0xFFFFFFu) * CH))[coq];
        if (u1 != INV) g1 = ((const float4*)(f + (long)(u1 & 0xFFFFFFu) * CH))[coq];
        #pragma unroll
        for (int b = 0; b < 4; ++b) {
            if (b >= nb) break;
            // stage current batch (compiler inserts vmcnt wait on g0/g1)
            *((float4*)(fbw + slot * 72 + coq * 4)) = g0;
            *((float4*)(fbw + slot * 72 + 36 + coq * 4)) = g1;
            // issue next batch's gathers (overlap with FMA below)
            unsigned nu0 = INV, nu1 = INV;
            float4 n0 = make_float4(0.f, 0.f, 0.f, 0.f), n1 = n0;
            if (b + 1 < 4 && b + 1 < nb) {
                nu0 = ent[2 * b + 2];
                nu1 = ent[2 * b + 3];
                if (nu0 != INV) n0 = ((const float4*)(f + (long)(nu0 & 0xFFFFFFu) * CH))[coq];
                if (nu1 != INV) n1 = ((const float4*)(f + (long)(nu1 & 0xFFFFFFu) * CH))[coq];
            }
            asm volatile("s_waitcnt lgkmcnt(0)" ::: "memory");
            __builtin_amdgcn_sched_barrier(0);
            float r00 = 0.f, r01 = 0.f, r02 = 0.f, r03 = 0.f;
            float r10 = 0.f, r11 = 0.f, r12 = 0.f, r13 = 0.f;
            #pragma unroll
            for (int c4 = 0; c4 < 8; ++c4) {
                float4 q0 = *((const float4*)(fbw + slot * 72 + c4 * 4));
                float4 q1 = *((const float4*)(fbw + slot * 72 + 36 + c4 * 4));
                const float* wp = wbw + c4 * 128 + coq * 4;
                float4 w0 = *((const float4*)(wp));
                float4 w1 = *((const float4*)(wp + 32));
                float4 w2 = *((const float4*)(wp + 64));
                float4 w3 = *((const float4*)(wp + 96));
                r00 += q0.x * w0.x; r01 += q0.x * w0.y; r02 += q0.x * w0.z; r03 += q0.x * w0.w;
                r00 += q0.y * w1.x; r01 += q0.y * w1.y; r02 += q0.y * w1.z; r03 += q0.y * w1.w;
                r00 += q0.z * w2.x; r01 += q0.z * w2.y; r02 += q0.z * w2.z; r03 += q0.z * w2.w;
                r00 += q0.w * w3.x; r01 += q0.w * w3.y; r02 += q0.w * w3.z; r03 += q0.w * w3.w;
                r10 += q1.x * w0.x; r11 += q1.x * w0.y; r12 += q1.x * w0.z; r13 += q1.x * w0.w;
                r10 += q1.y * w1.x; r11 += q1.y * w1.y; r12 += q1.y * w1.z; r13 += q1.y * w1.w;
                r10 += q1.z * w2.x; r11 += q1.z * w2.y; r12 += q1.z * w2.z; r13 += q1.z * w2.w;
                r10 += q1.w * w3.x; r11 += q1.w * w3.y; r12 += q1.w * w3.z; r13 += q1.w * w3.w;
            }
            if (u0 != INV) {
                float4* ap = (float4*)(accw + (int)(u0 >> 24) * 36 + coq * 4);
                float4 av = *ap;
                av.x += r00; av.y += r01; av.z += r02; av.w += r03;
                *ap = av;
            }
            if (u1 != INV) {
                float4* ap = (float4*)(accw + (int)(u1 >> 24) * 36 + coq * 4);
                float4 av = *ap;
                av.x += r10; av.y += r11; av.z += r12; av.w += r13;
                *ap = av;
            }
            u0 = nu0; u1 = nu1; g0 = n0; g1 = n1;
        }
    }
    __syncthreads();
    // reduce 4 wave planes + epilogue
    for (int cell = t; cell < 512; cell += 256) {
        int r = cell >> 3, q = cell & 7;
        int gi = (c << 6) + r;
        if (gi < count) {
            const int ro = r * 36 + q * 4;
            float4 s0 = *((const float4*)(acc + 0 * 2304 + ro));
            float4 s1 = *((const float4*)(acc + 1 * 2304 + ro));
            float4 s2 = *((const float4*)(acc + 2 * 2304 + ro));
            float4 s3 = *((const float4*)(acc + 3 * 2304 + ro));
            float4 b = ((const float4*)bias)[q];
            float4 o;
            o.x = s0.x + s1.x + s2.x + s3.x + b.x;
            o.y = s0.y + s1.y + s2.y + s3.y + b.y;
            o.z = s0.z + s1.z + s2.z + s3.z + b.z;
            o.w = s0.w + s1.w + s2.w + s3.w + b.w;
            int m = list[gi];
            if (ADD) {
                float4 a = ((const float4*)(addsrc + (long)m * CH))[q];
                o.x += a.x; o.y += a.y; o.z += a.z; o.w += a.w;
            }
            if (RELU) {
                o.x = fmaxf(o.x, 0.f); o.y = fmaxf(o.y, 0.f);
                o.z = fmaxf(o.z, 0.f); o.w = fmaxf(o.w, 0.f);
            }
            ((float4*)(out + (long)m * CH))[q] = o;
        }
    }
}

// ---------------- generative transpose conv k2 s2 ----------------

__global__ __launch_bounds__(256) void k_tconv(
    const float* __restrict__ h,
    const float* __restrict__ wt,
    const float* __restrict__ bt,
    float* __restrict__ out)
{
    __shared__ float wl[8 * 1060];
    for (int i = threadIdx.x; i < 8 * CH * CH; i += 256) {
        wl[(i >> 10) * 1060 + (i & 1023)] = wt[i];
    }
    __syncthreads();
    const int m = blockIdx.x * 256 + threadIdx.x;
    const int p = m >> 3, o = m & 7;
    float hr[CH], acc[CH];
    #pragma unroll
    for (int c4 = 0; c4 < 8; ++c4) {
        float4 v = ((const float4*)(h + (long)p * CH))[c4];
        hr[c4*4+0] = v.x; hr[c4*4+1] = v.y; hr[c4*4+2] = v.z; hr[c4*4+3] = v.w;
        float4 b = ((const float4*)bt)[c4];
        acc[c4*4+0] = b.x; acc[c4*4+1] = b.y; acc[c4*4+2] = b.z; acc[c4*4+3] = b.w;
    }
    const float* wb = wl + o * 1060;
    #pragma unroll
    for (int ci = 0; ci < CH; ++ci) {
        float hv = hr[ci];
        #pragma unroll
        for (int c4 = 0; c4 < 8; ++c4) {
            float4 w = *((const float4*)(wb + ci * CH + c4 * 4));
            acc[c4*4+0] += hv * w.x; acc[c4*4+1] += hv * w.y;
            acc[c4*4+2] += hv * w.z; acc[c4*4+3] += hv * w.w;
        }
    }
    #pragma unroll
    for (int c4 = 0; c4 < 8; ++c4) {
        ((float4*)(out + (long)m * CH))[c4] =
            make_float4(acc[c4*4+0], acc[c4*4+1], acc[c4*4+2], acc[c4*4+3]);
    }
}

// ---------------- classifier ----------------

__global__ __launch_bounds__(256) void k_classifier(
    const float* __restrict__ HS,
    const float* __restrict__ cw0, const float* __restrict__ cb0,
    const float* __restrict__ cw1, const float* __restrict__ cb1,
    const float* __restrict__ cw2, const float* __restrict__ cb2,
    float* __restrict__ outp, int so)
{
    __shared__ float w0[1024], w1[1024], w2[32], b0[32], b1[32];
    for (int i = threadIdx.x; i < 1024; i += 256) { w0[i] = cw0[i]; w1[i] = cw1[i]; }
    if (threadIdx.x < 32) {
        w2[threadIdx.x] = cw2[threadIdx.x];
        b0[threadIdx.x] = cb0[threadIdx.x];
        b1[threadIdx.x] = cb1[threadIdx.x];
    }
    __syncthreads();
    const int m = blockIdx.x * 256 + threadIdx.x;
    if (m >= M_ALL) return;
    if ((m & 7) != so) { outp[m] = 0.f; return; }
    float in[CH], h0[CH], h1[CH];
    #pragma unroll
    for (int c4 = 0; c4 < 8; ++c4) {
        float4 v = ((const float4*)(HS + (long)m * CH))[c4];
        in[c4*4+0] = v.x; in[c4*4+1] = v.y; in[c4*4+2] = v.z; in[c4*4+3] = v.w;
    }
    #pragma unroll
    for (int c = 0; c < CH; ++c) h0[c] = b0[c];
    #pragma unroll
    for (int ci = 0; ci < CH; ++ci) {
        float v = in[ci];
        #pragma unroll
        for (int c4 = 0; c4 < 8; ++c4) {
            float4 w = *((const float4*)(w0 + ci * CH + c4 * 4));
            h0[c4*4+0] += v * w.x; h0[c4*4+1] += v * w.y;
            h0[c4*4+2] += v * w.z; h0[c4*4+3] += v * w.w;
        }
    }
    #pragma unroll
    for (int c = 0; c < CH; ++c) { h0[c] = fmaxf(h0[c], 0.f); h1[c] = b1[c]; }
    #pragma unroll
    for (int ci = 0; ci < CH; ++ci) {
        float v = h0[ci];
        #pragma unroll
        for (int c4 = 0; c4 < 8; ++c4) {
            float4 w = *((const float4*)(w1 + ci * CH + c4 * 4));
            h1[c4*4+0] += v * w.x; h1[c4*4+1] += v * w.y;
            h1[c4*4+2] += v * w.z; h1[c4*4+3] += v * w.w;
        }
    }
    float o = cb2[0];
    #pragma unroll
    for (int ci = 0; ci < CH; ++ci) o += fmaxf(h1[ci], 0.f) * w2[ci];
    outp[m] = o;
}

// ---------------- host orchestration ----------------

extern "C" void kernel_launch(void* const* d_in, const int* in_sizes, int n_in,
                              void* d_out, int out_size, void* d_ws, size_t ws_size,
                              hipStream_t stream)
{
    (void)in_sizes; (void)n_in; (void)out_size; (void)ws_size;
    const float* x_low  = (const float*)d_in[0];
    const float* bi_w0  = (const float*)d_in[1];
    const float* bi_b0  = (const float*)d_in[2];
    const float* bi_w   = (const float*)d_in[3];
    const float* bi_b   = (const float*)d_in[4];
    const float* wt     = (const float*)d_in[5];
    const float* bt     = (const float*)d_in[6];
    const float* sw     = (const float*)d_in[7];
    const float* sb     = (const float*)d_in[8];
    const float* cw0    = (const float*)d_in[9];
    const float* cb0    = (const float*)d_in[10];
    const float* cw1    = (const float*)d_in[11];
    const float* cb1    = (const float*)d_in[12];
    const float* cw2    = (const float*)d_in[13];
    const float* cb2    = (const float*)d_in[14];
    const int* nbr_low  = (const int*)d_in[15];
    const int* nbr_u    = (const int*)d_in[16];
    const unsigned char* gtraw = (const unsigned char*)d_in[18];
    float* out = (float*)d_out;

    char* w = (char*)d_ws;
    size_t off = 0;
    auto carve = [&](size_t bytes) -> void* {
        void* p = w + off;
        off += (bytes + 255) & ~(size_t)255;
        return p;
    };
    float* feats = (float*)carve((size_t)M_ALL * CH * 4);
    float* A     = (float*)carve((size_t)M_ALL * CH * 4);
    float* X     = (float*)carve((size_t)M_ALL * CH * 4);
    float* HS    = (float*)carve((size_t)M_ALL * CH * 4);
    unsigned int* pent = (unsigned int*)carve((size_t)NCHMAX * NTAP * 64 * 4);
    int* pcnt    = (int*)carve((size_t)NCHMAX * NTAP * 4);
    int* list    = (int*)carve((size_t)M_ALL * 4);
    int* list_low= (int*)carve((size_t)N_LOW * 4);
    unsigned char* valid = (unsigned char*)carve(M_ALL);
    unsigned char* gt8   = (unsigned char*)carve(M_ALL);
    int* cnt     = (int*)carve(64 * 4);

    const size_t WL = 27648;       // 27*32*32

    k_init<<<1, 64, 0, stream>>>(cnt);
    k_gt_detect<<<512, 256, 0, stream>>>(gtraw, cnt);
    k_gt_norm<<<512, 256, 0, stream>>>(gtraw, gt8, cnt);
    k_iota<<<64, 256, 0, stream>>>(list_low);

    // ---- low-resolution block (exactly 256 chunks) ----
    k_conv_low0<<<(N_LOW * CH) / 256, 256, 0, stream>>>(x_low, nbr_low, bi_w0, bi_b0, A);
    const int GL = 256;
    k_pairs2<0><<<GL, 256, 0, stream>>>(nbr_low, list_low, cnt + 8, nullptr, pcnt, pent);
    k_convp<1,0><<<GL,256,0,stream>>>(A, X, nullptr, bi_w + 0*WL, bi_b + 0*32, list_low, cnt + 8, pcnt, pent);
    k_convp<0,1><<<GL,256,0,stream>>>(X, A, A,       bi_w + 1*WL, bi_b + 1*32, list_low, cnt + 8, pcnt, pent);
    k_convp<1,0><<<GL,256,0,stream>>>(A, X, nullptr, bi_w + 2*WL, bi_b + 2*32, list_low, cnt + 8, pcnt, pent);
    k_convp<0,1><<<GL,256,0,stream>>>(X, A, A,       bi_w + 3*WL, bi_b + 3*32, list_low, cnt + 8, pcnt, pent);
    k_convp<1,0><<<GL,256,0,stream>>>(A, X, nullptr, bi_w + 4*WL, bi_b + 4*32, list_low, cnt + 8, pcnt, pent);
    k_convp<0,1><<<GL,256,0,stream>>>(X, A, A,       bi_w + 5*WL, bi_b + 5*32, list_low, cnt + 8, pcnt, pent);
    k_convp<0,0><<<GL,256,0,stream>>>(A, X, nullptr, bi_w + 6*WL, bi_b + 6*32, list_low, cnt + 8, pcnt, pent);
    k_tconv<<<512, 256, 0, stream>>>(X, wt, bt, feats);

    // ---- 8 generative stages ----
    static const int order[8] = {0, 7, 1, 6, 5, 2, 3, 4};
    for (int s = 0; s < 8; ++s) {
        const int so = order[s];
        if (s == 0) k_compact<1><<<512,256,0,stream>>>(valid, gt8, nullptr, nullptr, nullptr, list, cnt + s, so);
        else        k_compact<0><<<512,256,0,stream>>>(valid, gt8, HS, feats, X, list, cnt + s, so);

        // stage-s valid set is a subset of the union of the first s+1 octant
        // slices -> count <= 16384*(s+1) -> chunks <= 256*(s+1)
        int GS = 256 * (s + 1);
        if (GS > NCHMAX) GS = NCHMAX;
        k_pairs2<1><<<GS, 256, 0, stream>>>(nbr_u, list, cnt + s, valid, pcnt, pent);

        const float* sws = sw + (size_t)s * 8 * WL;
        const float* sbs = sb + (size_t)s * 8 * 32;
        const float* F0  = (s == 0) ? feats : X;
        k_convp<1,0><<<GS,256,0,stream>>>(F0, A, nullptr, sws + 0*WL, sbs + 0*32, list, cnt + s, pcnt, pent);
        k_convp<1,0><<<GS,256,0,stream>>>(A,  X, nullptr, sws + 1*WL, sbs + 1*32, list, cnt + s, pcnt, pent);
        k_convp<0,1><<<GS,256,0,stream>>>(X,  A, A,       sws + 2*WL, sbs + 2*32, list, cnt + s, pcnt, pent);
        k_convp<1,0><<<GS,256,0,stream>>>(A,  X, nullptr, sws + 3*WL, sbs + 3*32, list, cnt + s, pcnt, pent);
        k_convp<0,1><<<GS,256,0,stream>>>(X,  A, A,       sws + 4*WL, sbs + 4*32, list, cnt + s, pcnt, pent);
        k_convp<1,0><<<GS,256,0,stream>>>(A,  X, nullptr, sws + 5*WL, sbs + 5*32, list, cnt + s, pcnt, pent);
        k_convp<0,1><<<GS,256,0,stream>>>(X,  A, A,       sws + 6*WL, sbs + 6*32, list, cnt + s, pcnt, pent);
        k_convp<0,0><<<GS,256,0,stream>>>(A, HS, nullptr, sws + 7*WL, sbs + 7*32, list, cnt + s, pcnt, pent);

        k_classifier<<<512,256,0,stream>>>(HS, cw0, cb0, cw1, cb1, cw2, cb2,
                                           out + (size_t)s * M_ALL, so);
    }
}